// Round 1
// baseline (87.559 us; speedup 1.0000x reference)
//
#include <hip/hip_runtime.h>

// LIF forward scan over T=6 timesteps.
// v = 0.5*v + I_t ; s = (v >= 1.0) ; v -= s
// Input  [T, N] float32, N = 64*128*32*32 = 8388608
// Output [T, N] float32 spikes.
// Memory-bound: 402 MB total traffic -> ~64 us floor at 6.3 TB/s.

#define V_DECAY     0.5f
#define V_THRESHOLD 1.0f
#define T_STEPS     6

__global__ __launch_bounds__(256) void lif_fwd_kernel(
    const float* __restrict__ in,   // [T, N]
    float* __restrict__ out,        // [T, N]
    long long n4)                   // N/4 float4 elements per time slice
{
    const float4* __restrict__ in4 = reinterpret_cast<const float4*>(in);
    float4* __restrict__ out4      = reinterpret_cast<float4*>(out);

    const long long stride = (long long)gridDim.x * blockDim.x;
    for (long long i = (long long)blockIdx.x * blockDim.x + threadIdx.x;
         i < n4; i += stride) {
        float va = 0.0f, vb = 0.0f, vc = 0.0f, vd = 0.0f;
#pragma unroll
        for (int t = 0; t < T_STEPS; ++t) {
            float4 x = in4[(long long)t * n4 + i];
            va = va * V_DECAY + x.x;
            vb = vb * V_DECAY + x.y;
            vc = vc * V_DECAY + x.z;
            vd = vd * V_DECAY + x.w;
            float sa = (va >= V_THRESHOLD) ? 1.0f : 0.0f;
            float sb = (vb >= V_THRESHOLD) ? 1.0f : 0.0f;
            float sc = (vc >= V_THRESHOLD) ? 1.0f : 0.0f;
            float sd = (vd >= V_THRESHOLD) ? 1.0f : 0.0f;
            va -= sa * V_THRESHOLD;
            vb -= sb * V_THRESHOLD;
            vc -= sc * V_THRESHOLD;
            vd -= sd * V_THRESHOLD;
            float4 s = make_float4(sa, sb, sc, sd);
            out4[(long long)t * n4 + i] = s;
        }
    }
}

extern "C" void kernel_launch(void* const* d_in, const int* in_sizes, int n_in,
                              void* d_out, int out_size, void* d_ws, size_t ws_size,
                              hipStream_t stream) {
    const float* in = (const float*)d_in[0];
    float* out = (float*)d_out;

    // in_sizes[0] = T*N total elements
    const long long total = (long long)in_sizes[0];
    const long long n = total / T_STEPS;     // neurons per time slice
    const long long n4 = n / 4;              // float4 elements per slice

    const int block = 256;
    long long want_blocks = (n4 + block - 1) / block;
    int grid = (int)(want_blocks < 2048 ? want_blocks : 2048);

    lif_fwd_kernel<<<grid, block, 0, stream>>>(in, out, n4);
}

// Round 3
// 77.808 us; speedup vs baseline: 1.1253x; 1.1253x over previous
//
#include <hip/hip_runtime.h>

// LIF forward scan over T=6 timesteps.
// v = 0.5*v + I_t ; s = (v >= 1.0) ; v -= s
// Input  [T, N] float32, N = 64*128*32*32 = 8388608
// Output [T, N] float32 spikes.
// Memory-bound: 402 MB total traffic -> ~64 us floor at 6.3 TB/s.
//
// R1: all 6 timestep loads issued up front (6 outstanding vmcnt), compute,
// then 6 stores; full grid (1 float4/thread); nontemporal hints (no reuse).
// R2 fix: __builtin_nontemporal_* needs a native clang vector type, not
// HIP_vector_type -> use ext_vector_type(4) float.

#define V_DECAY     0.5f
#define V_THRESHOLD 1.0f
#define T_STEPS     6

typedef float f32x4 __attribute__((ext_vector_type(4)));

__global__ __launch_bounds__(256) void lif_fwd_kernel(
    const f32x4* __restrict__ in4,   // [T, n4]
    f32x4* __restrict__ out4,        // [T, n4]
    long long n4)
{
    const long long i = (long long)blockIdx.x * blockDim.x + threadIdx.x;
    if (i >= n4) return;

    // Issue all 6 loads before any use: 6 outstanding global loads hide HBM latency.
    f32x4 x0 = __builtin_nontemporal_load(&in4[0 * n4 + i]);
    f32x4 x1 = __builtin_nontemporal_load(&in4[1 * n4 + i]);
    f32x4 x2 = __builtin_nontemporal_load(&in4[2 * n4 + i]);
    f32x4 x3 = __builtin_nontemporal_load(&in4[3 * n4 + i]);
    f32x4 x4 = __builtin_nontemporal_load(&in4[4 * n4 + i]);
    f32x4 x5 = __builtin_nontemporal_load(&in4[5 * n4 + i]);

    f32x4 v = {0.0f, 0.0f, 0.0f, 0.0f};
    f32x4 s0, s1, s2, s3, s4, s5;

#define LIF_STEP(X, S)                                                \
    do {                                                              \
        v = v * V_DECAY + (X);                                        \
        (S).x = (v.x >= V_THRESHOLD) ? 1.0f : 0.0f;                   \
        (S).y = (v.y >= V_THRESHOLD) ? 1.0f : 0.0f;                   \
        (S).z = (v.z >= V_THRESHOLD) ? 1.0f : 0.0f;                   \
        (S).w = (v.w >= V_THRESHOLD) ? 1.0f : 0.0f;                   \
        v = v - (S) * V_THRESHOLD;                                    \
    } while (0)

    LIF_STEP(x0, s0);
    LIF_STEP(x1, s1);
    LIF_STEP(x2, s2);
    LIF_STEP(x3, s3);
    LIF_STEP(x4, s4);
    LIF_STEP(x5, s5);
#undef LIF_STEP

    __builtin_nontemporal_store(s0, &out4[0 * n4 + i]);
    __builtin_nontemporal_store(s1, &out4[1 * n4 + i]);
    __builtin_nontemporal_store(s2, &out4[2 * n4 + i]);
    __builtin_nontemporal_store(s3, &out4[3 * n4 + i]);
    __builtin_nontemporal_store(s4, &out4[4 * n4 + i]);
    __builtin_nontemporal_store(s5, &out4[5 * n4 + i]);
}

extern "C" void kernel_launch(void* const* d_in, const int* in_sizes, int n_in,
                              void* d_out, int out_size, void* d_ws, size_t ws_size,
                              hipStream_t stream) {
    const float* in = (const float*)d_in[0];
    float* out = (float*)d_out;

    const long long total = (long long)in_sizes[0];
    const long long n = total / T_STEPS;     // neurons per time slice
    const long long n4 = n / 4;              // float4 elements per slice

    const int block = 256;
    const int grid = (int)((n4 + block - 1) / block);

    lif_fwd_kernel<<<grid, block, 0, stream>>>(
        reinterpret_cast<const f32x4*>(in),
        reinterpret_cast<f32x4*>(out),
        n4);
}

// Round 5
// 64.432 us; speedup vs baseline: 1.3589x; 1.2076x over previous
//
#include <hip/hip_runtime.h>

// LIF forward scan over T=6 timesteps.
// v = 0.5*v + I_t ; s = (v >= 1.0) ; v -= s
// Input  [T, N] float32, N = 64*128*32*32 = 8388608 (201 MB — fits in 256 MB L3)
// Output [T, N] float32 spikes (201 MB, never re-read).
// Memory-bound. 402 MB total; HBM floor ~64 us, lower if input stays L3-resident.
//
// R1: all 6 timestep loads issued up front (6 outstanding vmcnt), compute,
// then 6 stores; full grid (1 float4/thread).
// R2 fix: ext_vector_type(4) float for nontemporal builtins.
// R4: loads CACHEABLE (input re-read every replay -> keep it in L3);
//     stores stay nontemporal (output never re-read; don't evict input).
// R5: resubmit of R4 (container died — no data).

#define V_DECAY     0.5f
#define V_THRESHOLD 1.0f
#define T_STEPS     6

typedef float f32x4 __attribute__((ext_vector_type(4)));

__global__ __launch_bounds__(256) void lif_fwd_kernel(
    const f32x4* __restrict__ in4,   // [T, n4]
    f32x4* __restrict__ out4,        // [T, n4]
    long long n4)
{
    const long long i = (long long)blockIdx.x * blockDim.x + threadIdx.x;
    if (i >= n4) return;

    // Issue all 6 loads before any use: 6 outstanding global loads hide HBM latency.
    f32x4 x0 = in4[0 * n4 + i];
    f32x4 x1 = in4[1 * n4 + i];
    f32x4 x2 = in4[2 * n4 + i];
    f32x4 x3 = in4[3 * n4 + i];
    f32x4 x4 = in4[4 * n4 + i];
    f32x4 x5 = in4[5 * n4 + i];

    f32x4 v = {0.0f, 0.0f, 0.0f, 0.0f};
    f32x4 s0, s1, s2, s3, s4, s5;

#define LIF_STEP(X, S)                                                \
    do {                                                              \
        v = v * V_DECAY + (X);                                        \
        (S).x = (v.x >= V_THRESHOLD) ? 1.0f : 0.0f;                   \
        (S).y = (v.y >= V_THRESHOLD) ? 1.0f : 0.0f;                   \
        (S).z = (v.z >= V_THRESHOLD) ? 1.0f : 0.0f;                   \
        (S).w = (v.w >= V_THRESHOLD) ? 1.0f : 0.0f;                   \
        v = v - (S) * V_THRESHOLD;                                    \
    } while (0)

    LIF_STEP(x0, s0);
    LIF_STEP(x1, s1);
    LIF_STEP(x2, s2);
    LIF_STEP(x3, s3);
    LIF_STEP(x4, s4);
    LIF_STEP(x5, s5);
#undef LIF_STEP

    __builtin_nontemporal_store(s0, &out4[0 * n4 + i]);
    __builtin_nontemporal_store(s1, &out4[1 * n4 + i]);
    __builtin_nontemporal_store(s2, &out4[2 * n4 + i]);
    __builtin_nontemporal_store(s3, &out4[3 * n4 + i]);
    __builtin_nontemporal_store(s4, &out4[4 * n4 + i]);
    __builtin_nontemporal_store(s5, &out4[5 * n4 + i]);
}

extern "C" void kernel_launch(void* const* d_in, const int* in_sizes, int n_in,
                              void* d_out, int out_size, void* d_ws, size_t ws_size,
                              hipStream_t stream) {
    const float* in = (const float*)d_in[0];
    float* out = (float*)d_out;

    const long long total = (long long)in_sizes[0];
    const long long n = total / T_STEPS;     // neurons per time slice
    const long long n4 = n / 4;              // float4 elements per slice

    const int block = 256;
    const int grid = (int)((n4 + block - 1) / block);

    lif_fwd_kernel<<<grid, block, 0, stream>>>(
        reinterpret_cast<const f32x4*>(in),
        reinterpret_cast<f32x4*>(out),
        n4);
}